// Round 6
// baseline (486.963 us; speedup 1.0000x reference)
//
#include <hip/hip_runtime.h>
#include <math.h>

typedef float f32x4 __attribute__((ext_vector_type(4)));
typedef __bf16 bf16x8 __attribute__((ext_vector_type(8)));
typedef unsigned int u32;
typedef u32 u32x4 __attribute__((ext_vector_type(4)));

#define AS1 __attribute__((address_space(1)))
#define AS3 __attribute__((address_space(3)))

static __device__ __forceinline__ void gload16(const void* g, void* l) {
    __builtin_amdgcn_global_load_lds((const AS1 u32*)g, (AS3 u32*)l, 16, 0, 0);
}
static __device__ __forceinline__ f32x4 mfma16(bf16x8 a, bf16x8 b, f32x4 c) {
    return __builtin_amdgcn_mfma_f32_16x16x32_bf16(a, b, c, 0, 0, 0);
}
static __device__ __forceinline__ float exp2fast(float x) {
    return __builtin_amdgcn_exp2f(x);
}

// ---------------------------------------------------------------------------
// fp32 -> bf16 bulk convert
// ---------------------------------------------------------------------------
__global__ __launch_bounds__(256)
void convert_kernel(const float* __restrict__ in, __bf16* __restrict__ out)
{
    const size_t i = ((size_t)blockIdx.x * 256 + threadIdx.x) * 8;
    f32x4 a = *(const f32x4*)(in + i);
    f32x4 b = *(const f32x4*)(in + i + 4);
    bf16x8 o;
    #pragma unroll
    for (int j = 0; j < 4; ++j) { o[j] = (__bf16)a[j]; o[j + 4] = (__bf16)b[j]; }
    *(bf16x8*)(out + i) = o;
}

// ---------------------------------------------------------------------------
// QKV GEMM 256x256, BK=64, 8 waves. 8-phase counted-vmcnt schedule:
// Stage groups (16KB, 2 gloads each) keyed by read-deadline:
//   A0 = A rows read at P1 ({0-63,128-191}),  B0 = B rows read at P1&P4,
//   B1 = B rows read at P2,                   A1 = A rows read at P3.
// Tile t stages t+1's groups at P1..P4 (all into nxt buffer - idle, so NO
// early overwrite). Deadlines land in t+1 => uniform vmcnt(6) at P1..P3:
//   P1: outstanding {A0,B0,B1,A1}(t)+A0(t+1)=10 -> oldest 4 = A0,B0(t) ok
//   P2: outstanding {B1,A1}(t)+{A0,B0}(t+1)=8  -> oldest 2 = B1(t)    ok
//   P3: outstanding {A1}(t)+{A0,B0,B1}(t+1)=8  -> oldest 2 = A1(t)    ok
//   P4: reads B0(t) (confirmed at P1), no wait.
// Phase = {stage, [vmcnt(6)], barrier, ds_reads, setprio-MFMAx16, barrier}.
// Tile order by-major (bx fast) + m204 XCD chunk -> A panel shared in-L2.
// ---------------------------------------------------------------------------
__global__ __launch_bounds__(512, 2)
void gemm_qkv256(const __bf16* __restrict__ A, const __bf16* __restrict__ Bw,
                 const float* __restrict__ bias,
                 __bf16* __restrict__ q_out, __bf16* __restrict__ k_out,
                 __bf16* __restrict__ v_out)
{
    constexpr int M = 16400;
    constexpr int K = 1024;
    constexpr int NKT = 16;
    constexpr int NWG = 12 * 65;       // 780

    __shared__ __align__(16) __bf16 ldsA[2][256 * 64];
    __shared__ __align__(16) __bf16 ldsB[2][256 * 64];

    const int tid  = threadIdx.x;
    const int lane = tid & 63;
    const int wv   = tid >> 6;
    const int wr   = wv >> 2;          // 0..1  M half
    const int wc   = wv & 3;           // 0..3  N quarter
    const int fr   = lane & 15, fq = lane >> 4;

    // m204 bijective XCD chunk, tiles ordered by-major (bx fast)
    int tile;
    {
        constexpr int Q = NWG / 8, R = NWG % 8;   // 97, 4
        const int x = blockIdx.x & 7, j = blockIdx.x >> 3;
        tile = (x < R ? x * (Q + 1) : R * (Q + 1) + (x - R) * Q) + j;
    }
    const int by = tile / 12, bx = tile % 12;
    const int m0 = by * 256, n0 = bx * 256;

    // ---- staging precompute ----
    // A group g (g=0: P1-rows {0-63,128-191}; g=1: P3-rows): slot s=l*512+tid
    const __bf16* aSrc[2][2]; int aDst[2][2];
    #pragma unroll
    for (int g = 0; g < 2; ++g)
        #pragma unroll
        for (int l = 0; l < 2; ++l) {
            const int s    = l * 512 + tid;
            const int sr   = s >> 3, gran = s & 7;
            const int row  = (sr & 63) + g * 64 + ((sr >> 6) << 7);
            const int c    = gran ^ (row & 7);
            int m = m0 + row; if (m > M - 1) m = M - 1;
            aSrc[g][l] = A + (size_t)m * K + c * 8;
            aDst[g][l] = (row * 8 + gran) * 8;
        }
    // B group n: rows q*64 + n*32 + 0..31
    const __bf16* bSrc[2][2]; int bDst[2][2];
    #pragma unroll
    for (int n = 0; n < 2; ++n)
        #pragma unroll
        for (int l = 0; l < 2; ++l) {
            const int q   = l * 2 + (tid >> 8);
            const int p   = tid & 255;
            const int row = q * 64 + n * 32 + (p >> 3);
            const int g   = p & 7;
            const int c   = g ^ (row & 7);
            bSrc[n][l] = Bw + (size_t)(n0 + row) * K + c * 8;
            bDst[n][l] = (row * 8 + g) * 8;
        }

#define STAGE_A(g, nb, ko) { \
    gload16(aSrc[g][0] + (ko), &ldsA[nb][aDst[g][0]]); \
    gload16(aSrc[g][1] + (ko), &ldsA[nb][aDst[g][1]]); }
#define STAGE_B(n, nb, ko) { \
    gload16(bSrc[n][0] + (ko), &ldsB[nb][bDst[n][0]]); \
    gload16(bSrc[n][1] + (ko), &ldsB[nb][bDst[n][1]]); }
#define WAIT6_BAR  asm volatile("s_waitcnt vmcnt(6)\ns_barrier" ::: "memory")
#define BAR        asm volatile("s_barrier" ::: "memory")

    f32x4 acc[8][4];
    #pragma unroll
    for (int i = 0; i < 8; ++i)
        #pragma unroll
        for (int j = 0; j < 4; ++j)
            acc[i][j] = f32x4{0.f, 0.f, 0.f, 0.f};

    const int slot0 = ((0 + fq) ^ (fr & 7)) * 8;
    const int slot1 = ((4 + fq) ^ (fr & 7)) * 8;
    const int arow  = wr * 128 + fr;
    const int brow  = wc * 64 + fr;

    // ---- prologue: tile0's 4 groups, in ledger order ----
    STAGE_A(0, 0, 0); STAGE_B(0, 0, 0); STAGE_B(1, 0, 0); STAGE_A(1, 0, 0);

    bf16x8 a[4][2], b[2][2];
    for (int t = 0; t < NKT; ++t) {
        const int cur = t & 1, nxt = cur ^ 1;
        const int ko  = (t + 1 < NKT ? t + 1 : NKT - 1) * 64;

        // ======== P1: Q1 = acc[0..3][0..1]  (reads A0, B0) ========
        STAGE_A(0, nxt, ko);
        WAIT6_BAR;
        #pragma unroll
        for (int i = 0; i < 4; ++i) {
            a[i][0] = *(const bf16x8*)&ldsA[cur][(arow + i * 16) * 64 + slot0];
            a[i][1] = *(const bf16x8*)&ldsA[cur][(arow + i * 16) * 64 + slot1];
        }
        #pragma unroll
        for (int j = 0; j < 2; ++j) {
            b[j][0] = *(const bf16x8*)&ldsB[cur][(brow + j * 16) * 64 + slot0];
            b[j][1] = *(const bf16x8*)&ldsB[cur][(brow + j * 16) * 64 + slot1];
        }
        __builtin_amdgcn_s_setprio(1);
        #pragma unroll
        for (int ks = 0; ks < 2; ++ks)
            #pragma unroll
            for (int i = 0; i < 4; ++i)
                #pragma unroll
                for (int j = 0; j < 2; ++j)
                    acc[i][j] = mfma16(a[i][ks], b[j][ks], acc[i][j]);
        __builtin_amdgcn_s_setprio(0);
        BAR;

        // ======== P2: Q2 = acc[0..3][2..3]  (reads B1; a carried) ========
        STAGE_B(0, nxt, ko);
        WAIT6_BAR;
        #pragma unroll
        for (int j = 0; j < 2; ++j) {
            b[j][0] = *(const bf16x8*)&ldsB[cur][(brow + 32 + j * 16) * 64 + slot0];
            b[j][1] = *(const bf16x8*)&ldsB[cur][(brow + 32 + j * 16) * 64 + slot1];
        }
        __builtin_amdgcn_s_setprio(1);
        #pragma unroll
        for (int ks = 0; ks < 2; ++ks)
            #pragma unroll
            for (int i = 0; i < 4; ++i)
                #pragma unroll
                for (int j = 0; j < 2; ++j)
                    acc[i][2 + j] = mfma16(a[i][ks], b[j][ks], acc[i][2 + j]);
        __builtin_amdgcn_s_setprio(0);
        BAR;

        // ======== P3: Q4 = acc[4..7][2..3]  (reads A1; b_hi carried) ========
        STAGE_B(1, nxt, ko);
        WAIT6_BAR;
        #pragma unroll
        for (int i = 0; i < 4; ++i) {
            a[i][0] = *(const bf16x8*)&ldsA[cur][(arow + 64 + i * 16) * 64 + slot0];
            a[i][1] = *(const bf16x8*)&ldsA[cur][(arow + 64 + i * 16) * 64 + slot1];
        }
        __builtin_amdgcn_s_setprio(1);
        #pragma unroll
        for (int ks = 0; ks < 2; ++ks)
            #pragma unroll
            for (int i = 0; i < 4; ++i)
                #pragma unroll
                for (int j = 0; j < 2; ++j)
                    acc[4 + i][2 + j] = mfma16(a[i][ks], b[j][ks], acc[4 + i][2 + j]);
        __builtin_amdgcn_s_setprio(0);
        BAR;

        // ======== P4: Q3 = acc[4..7][0..1]  (re-reads B0; no wait) ========
        STAGE_A(1, nxt, ko);
        BAR;
        #pragma unroll
        for (int j = 0; j < 2; ++j) {
            b[j][0] = *(const bf16x8*)&ldsB[cur][(brow + j * 16) * 64 + slot0];
            b[j][1] = *(const bf16x8*)&ldsB[cur][(brow + j * 16) * 64 + slot1];
        }
        __builtin_amdgcn_s_setprio(1);
        #pragma unroll
        for (int ks = 0; ks < 2; ++ks)
            #pragma unroll
            for (int i = 0; i < 4; ++i)
                #pragma unroll
                for (int j = 0; j < 2; ++j)
                    acc[4 + i][j] = mfma16(a[i][ks], b[j][ks], acc[4 + i][j]);
        __builtin_amdgcn_s_setprio(0);
        BAR;
    }
    asm volatile("s_waitcnt vmcnt(0)" ::: "memory");

    // ---- epilogue: scatter to q/k/v [b,h,s,d] ----
    #pragma unroll
    for (int ni = 0; ni < 4; ++ni) {
        const int col = n0 + wc * 64 + ni * 16 + fr;
        const float bv = bias[col];
        const int head = col / 192;
        const int tsel = (col >> 6) % 3;
        const int d    = col & 63;
        __bf16* dst = (tsel == 0) ? q_out : (tsel == 1 ? k_out : v_out);
        const float scale = (tsel == 0) ? 0.18033688011112042f : 1.0f;
        #pragma unroll
        for (int mi = 0; mi < 8; ++mi) {
            #pragma unroll
            for (int j = 0; j < 4; ++j) {
                const int m = m0 + wr * 128 + mi * 16 + fq * 4 + j;
                if (m < M) {
                    const int bb = m / 1025;
                    const int ss = m - bb * 1025;
                    dst[(((size_t)(bb * 16 + head)) * 1025 + ss) * 64 + d] =
                        (__bf16)((acc[mi][ni][j] + bv) * scale);
                }
            }
        }
    }
#undef STAGE_A
#undef STAGE_B
#undef WAIT6_BAR
#undef BAR
}

// ---------------------------------------------------------------------------
// Dense-out GEMM: 128x128 (R3 structure) + XCD chunk, bx-fast A-sharing
// ---------------------------------------------------------------------------
__global__ __launch_bounds__(256)
void gemm_dense128(const __bf16* __restrict__ A, const __bf16* __restrict__ Bw,
                   const float* __restrict__ bias, float* __restrict__ f_out)
{
    constexpr int M = 16400;
    constexpr int K = 1024;

    __shared__ __align__(16) __bf16 As[128 * 64];
    __shared__ __align__(16) __bf16 Bs[128 * 64];

    const int tid  = threadIdx.x;
    const int lane = tid & 63;
    const int wv   = tid >> 6;
    const int wr   = wv >> 1, wc = wv & 1;
    const int fr   = lane & 15, fq = lane >> 4;

    // XCD chunk: 1032 = 8 x 129, bx-fast (consecutive tiles share A panel)
    const int xx = blockIdx.x & 7, jj = blockIdx.x >> 3;
    const int tile = xx * 129 + jj;
    const int m0 = (tile >> 3) * 128;
    const int n0 = (tile & 7) * 128;

    const __bf16* aptr[4];
    const __bf16* bptr[4];
    int loff[4];
    #pragma unroll
    for (int qd = 0; qd < 4; ++qd) {
        const int s  = qd * 256 + tid;
        const int r  = s >> 3;
        const int c  = (s & 7) ^ (r & 7);
        loff[qd] = s * 8;
        int ar = m0 + r; if (ar > M - 1) ar = M - 1;
        aptr[qd] = A  + (size_t)ar * K + c * 8;
        bptr[qd] = Bw + (size_t)(n0 + r) * K + c * 8;
    }

    f32x4 acc[4][4];
    #pragma unroll
    for (int i = 0; i < 4; ++i)
        #pragma unroll
        for (int j = 0; j < 4; ++j)
            acc[i][j] = f32x4{0.f, 0.f, 0.f, 0.f};

    for (int kt = 0; kt < K / 64; ++kt) {
        const int kof = kt * 64;
        #pragma unroll
        for (int qd = 0; qd < 4; ++qd) {
            gload16(aptr[qd] + kof, &As[loff[qd]]);
            gload16(bptr[qd] + kof, &Bs[loff[qd]]);
        }
        __syncthreads();

        #pragma unroll
        for (int ks = 0; ks < 2; ++ks) {
            bf16x8 a[4], b[4];
            #pragma unroll
            for (int i = 0; i < 4; ++i) {
                const int ra = wr * 64 + i * 16 + fr;
                const int rb = wc * 64 + i * 16 + fr;
                const int cg = ((ks * 4 + fq) ^ (fr & 7)) * 8;
                a[i] = *(const bf16x8*)&As[ra * 64 + cg];
                b[i] = *(const bf16x8*)&Bs[rb * 64 + cg];
            }
            #pragma unroll
            for (int i = 0; i < 4; ++i)
                #pragma unroll
                for (int j = 0; j < 4; ++j)
                    acc[i][j] = mfma16(a[i], b[j], acc[i][j]);
        }
        __syncthreads();
    }

    #pragma unroll
    for (int ni = 0; ni < 4; ++ni) {
        const int col = n0 + wc * 64 + ni * 16 + fr;
        const float bv = bias[col];
        #pragma unroll
        for (int mi = 0; mi < 4; ++mi) {
            #pragma unroll
            for (int j = 0; j < 4; ++j) {
                const int m = m0 + wr * 64 + mi * 16 + fq * 4 + j;
                if (m < M) f_out[(size_t)m * 1024 + col] = acc[mi][ni][j] + bv;
            }
        }
    }
}

// ---------------------------------------------------------------------------
// V transpose: [bh][s][64] -> [bh][64][S2=1088]
// ---------------------------------------------------------------------------
__global__ __launch_bounds__(256)
void transpose_v(const __bf16* __restrict__ vb, __bf16* __restrict__ vt)
{
    constexpr int S = 1025, S2 = 1088;
    const int bh = blockIdx.y;
    const int s0 = blockIdx.x * 64;
    const int sr = threadIdx.x >> 2, sq = threadIdx.x & 3;
    int srow = s0 + sr; if (srow > S - 1) srow = S - 1;
    const __bf16* src = vb + ((size_t)bh * S + srow) * 64 + sq * 16;
    bf16x8 v0 = *(const bf16x8*)src;
    bf16x8 v1 = *(const bf16x8*)(src + 8);
    __bf16* dst = vt + (size_t)bh * 64 * S2 + s0 + sr;
    #pragma unroll
    for (int i = 0; i < 8; ++i) {
        dst[(size_t)(sq * 16 + i) * S2]     = v0[i];
        dst[(size_t)(sq * 16 + 8 + i) * S2] = v1[i];
    }
}

// ---------------------------------------------------------------------------
// Flash attention, swapped QK^T (R3 body) + XCD chunk (qt fast per bh)
// ---------------------------------------------------------------------------
__global__ __launch_bounds__(256)
void attn_kernel(const __bf16* __restrict__ qb, const __bf16* __restrict__ kb,
                 const __bf16* __restrict__ vtb, __bf16* __restrict__ ctxb)
{
    constexpr int S = 1025, S2 = 1088;
    const int tid  = threadIdx.x;
    const int lane = tid & 63;
    const int w    = tid >> 6;
    const int fr   = lane & 15, fq = lane >> 4;

    // XCD chunk: 4352 = 8 x 544; qt fast -> same-head blocks co-resident
    const int xx = blockIdx.x & 7, jj = blockIdx.x >> 3;
    const int tile = xx * 544 + jj;
    const int bh = tile / 17;
    const int q0 = (tile % 17) * 64;
    const int bb = bh >> 4, hh = bh & 15;

    const __bf16* qp = qb  + (size_t)bh * S * 64;
    const __bf16* kp = kb  + (size_t)bh * S * 64;
    const __bf16* vp = vtb + (size_t)bh * 64 * S2;

    __shared__ __align__(16) __bf16 Ks[64 * 64];
    __shared__ __align__(16) __bf16 Vs[64 * 64];
    __shared__ u32 Ps[4][16 * 33];

    const int s0i = tid, s1i = tid + 256;
    const int r0 = s0i >> 3, g0 = (s0i & 7) ^ (r0 & 7);
    const int r1 = s1i >> 3, g1 = (s1i & 7) ^ (r1 & 7);
    const __bf16* vsrc0 = vp + (size_t)r0 * S2 + g0 * 8;
    const __bf16* vsrc1 = vp + (size_t)r1 * S2 + g1 * 8;

    int qrow = q0 + w * 16 + fr; if (qrow > S - 1) qrow = S - 1;
    const bf16x8 qa0 = *(const bf16x8*)(qp + (size_t)qrow * 64 + fq * 8);
    const bf16x8 qa1 = *(const bf16x8*)(qp + (size_t)qrow * 64 + 32 + fq * 8);

    f32x4 ctx[4];
    #pragma unroll
    for (int di = 0; di < 4; ++di) ctx[di] = f32x4{0.f, 0.f, 0.f, 0.f};
    float mrow = -1e30f;
    float lrow = 0.f;

    u32* psrow_w = &Ps[w][fr * 33];

    for (int kt = 0; kt < 17; ++kt) {
        const int kv0 = kt * 64;
        {
            int kr0 = kv0 + r0; if (kr0 > S - 1) kr0 = S - 1;
            int kr1 = kv0 + r1; if (kr1 > S - 1) kr1 = S - 1;
            gload16(kp + (size_t)kr0 * 64 + g0 * 8, &Ks[s0i * 8]);
            gload16(kp + (size_t)kr1 * 64 + g1 * 8, &Ks[s1i * 8]);
            gload16(vsrc0 + kv0, &Vs[s0i * 8]);
            gload16(vsrc1 + kv0, &Vs[s1i * 8]);
        }
        __syncthreads();

        f32x4 sc[4];
        #pragma unroll
        for (int ni = 0; ni < 4; ++ni) {
            const int row = ni * 16 + fr;
            bf16x8 kf0 = *(const bf16x8*)&Ks[row * 64 + ((fq    ) ^ (row & 7)) * 8];
            bf16x8 kf1 = *(const bf16x8*)&Ks[row * 64 + ((fq + 4) ^ (row & 7)) * 8];
            f32x4 z = f32x4{0.f, 0.f, 0.f, 0.f};
            z = mfma16(kf0, qa0, z);
            sc[ni] = mfma16(kf1, qa1, z);
        }
        if (kv0 + 64 > S) {
            #pragma unroll
            for (int ni = 0; ni < 4; ++ni)
                #pragma unroll
                for (int j = 0; j < 4; ++j)
                    if (kv0 + ni * 16 + fq * 4 + j >= S) sc[ni][j] = -1e30f;
        }

        float mt = sc[0][0];
        #pragma unroll
        for (int ni = 0; ni < 4; ++ni)
            #pragma unroll
            for (int j = 0; j < 4; ++j) mt = fmaxf(mt, sc[ni][j]);
        mt = fmaxf(mt, __shfl_xor(mt, 16, 64));
        mt = fmaxf(mt, __shfl_xor(mt, 32, 64));

        if (__any(mt > mrow + 8.0f)) {
            const float mnew = fmaxf(mrow, mt);
            const float alpha = exp2fast(mrow - mnew);
            mrow = mnew;
            lrow *= alpha;
            float av[4];
            #pragma unroll
            for (int j = 0; j < 4; ++j) av[j] = __shfl(alpha, fq * 4 + j, 64);
            #pragma unroll
            for (int di = 0; di < 4; ++di) {
                ctx[di][0] *= av[0]; ctx[di][1] *= av[1];
                ctx[di][2] *= av[2]; ctx[di][3] *= av[3];
            }
        }

        float p[4][4];
        float s = 0.f;
        #pragma unroll
        for (int ni = 0; ni < 4; ++ni)
            #pragma unroll
            for (int j = 0; j < 4; ++j) {
                p[ni][j] = exp2fast(sc[ni][j] - mrow);
                s += p[ni][j];
            }
        s += __shfl_xor(s, 16, 64);
        s += __shfl_xor(s, 32, 64);
        lrow += s;

        #pragma unroll
        for (int ni = 0; ni < 4; ++ni) {
            #pragma unroll
            for (int h = 0; h < 2; ++h) {
                unsigned short lo = __builtin_bit_cast(unsigned short, (__bf16)p[ni][2 * h]);
                unsigned short hi = __builtin_bit_cast(unsigned short, (__bf16)p[ni][2 * h + 1]);
                psrow_w[fq * 8 + ni * 2 + h] = (u32)lo | ((u32)hi << 16);
            }
        }
        u32x4 pav[2];
        #pragma unroll
        for (int ks = 0; ks < 2; ++ks)
            #pragma unroll
            for (int t = 0; t < 4; ++t) {
                const int slot = (2 * (fq & 1) + (t >> 1)) * 8
                               + (2 * ks + (fq >> 1)) * 2 + (t & 1);
                pav[ks][t] = psrow_w[slot];
            }

        #pragma unroll
        for (int ks = 0; ks < 2; ++ks) {
            const bf16x8 pa = __builtin_bit_cast(bf16x8, pav[ks]);
            #pragma unroll
            for (int di = 0; di < 4; ++di) {
                const int row = di * 16 + fr;
                bf16x8 vf = *(const bf16x8*)&Vs[row * 64 + ((ks * 4 + fq) ^ (row & 7)) * 8];
                ctx[di] = mfma16(pa, vf, ctx[di]);
            }
        }
        __syncthreads();
    }

    float linv[4];
    #pragma unroll
    for (int j = 0; j < 4; ++j) linv[j] = 1.0f / __shfl(lrow, fq * 4 + j, 64);
    #pragma unroll
    for (int di = 0; di < 4; ++di) {
        #pragma unroll
        for (int j = 0; j < 4; ++j) {
            const int qg = q0 + w * 16 + fq * 4 + j;
            if (qg < S) {
                ctxb[((size_t)bb * 1025 + qg) * 1024 + hh * 64 + di * 16 + fr] =
                    (__bf16)(ctx[di][j] * linv[j]);
            }
        }
    }
}

// ---------------------------------------------------------------------------
extern "C" void kernel_launch(void* const* d_in, const int* in_sizes, int n_in,
                              void* d_out, int out_size, void* d_ws, size_t ws_size,
                              hipStream_t stream)
{
    const float* hs      = (const float*)d_in[0];
    const float* w_qkv   = (const float*)d_in[1];
    const float* b_qkv   = (const float*)d_in[2];
    const float* w_dense = (const float*)d_in[3];
    const float* b_dense = (const float*)d_in[4];

    const size_t nHS = (size_t)16 * 1025 * 1024;
    const size_t nWQ = (size_t)3072 * 1024;
    const size_t nWD = (size_t)1024 * 1024;

    __bf16* hsb     = (__bf16*)d_ws;
    __bf16* wqkvb   = hsb + nHS;
    __bf16* wdenseb = wqkvb + nWQ;
    __bf16* qb      = wdenseb + nWD;
    __bf16* kb      = qb + nHS;
    __bf16* vb      = kb + nHS;
    __bf16* ctxb    = vb + nHS;
    __bf16* vtb     = ctxb + nHS;

    dim3 blk(256);
    convert_kernel<<<dim3((unsigned)(nHS / 2048)), blk, 0, stream>>>(hs, hsb);
    convert_kernel<<<dim3((unsigned)(nWQ / 2048)), blk, 0, stream>>>(w_qkv, wqkvb);
    convert_kernel<<<dim3((unsigned)(nWD / 2048)), blk, 0, stream>>>(w_dense, wdenseb);

    gemm_qkv256<<<dim3(12 * 65), dim3(512), 0, stream>>>(
        hsb, wqkvb, b_qkv, qb, kb, vb);

    transpose_v<<<dim3(17, 256), blk, 0, stream>>>(vb, vtb);

    attn_kernel<<<dim3(8 * 544), blk, 0, stream>>>(qb, kb, vtb, ctxb);

    gemm_dense128<<<dim3(8 * 129), blk, 0, stream>>>(
        ctxb, wdenseb, b_dense, (float*)d_out);
}

// Round 7
// 437.707 us; speedup vs baseline: 1.1125x; 1.1125x over previous
//
#include <hip/hip_runtime.h>
#include <math.h>

typedef float f32x4 __attribute__((ext_vector_type(4)));
typedef __bf16 bf16x8 __attribute__((ext_vector_type(8)));
typedef unsigned int u32;
typedef u32 u32x4 __attribute__((ext_vector_type(4)));

#define AS1 __attribute__((address_space(1)))
#define AS3 __attribute__((address_space(3)))

static __device__ __forceinline__ void gload16(const void* g, void* l) {
    __builtin_amdgcn_global_load_lds((const AS1 u32*)g, (AS3 u32*)l, 16, 0, 0);
}
static __device__ __forceinline__ f32x4 mfma16(bf16x8 a, bf16x8 b, f32x4 c) {
    return __builtin_amdgcn_mfma_f32_16x16x32_bf16(a, b, c, 0, 0, 0);
}
static __device__ __forceinline__ float exp2fast(float x) {
    return __builtin_amdgcn_exp2f(x);
}

// ---------------------------------------------------------------------------
// fused fp32 -> bf16 convert over 3 segments (each a multiple of 2048 elems)
// ---------------------------------------------------------------------------
__global__ __launch_bounds__(256)
void convert3_kernel(const float* __restrict__ in0, __bf16* __restrict__ out0, int nb0,
                     const float* __restrict__ in1, __bf16* __restrict__ out1, int nb1,
                     const float* __restrict__ in2, __bf16* __restrict__ out2)
{
    int b = blockIdx.x;
    const float* in; __bf16* out;
    if (b < nb0)            { in = in0; out = out0; }
    else if (b < nb0 + nb1) { in = in1; out = out1; b -= nb0; }
    else                    { in = in2; out = out2; b -= nb0 + nb1; }
    const size_t i = ((size_t)b * 256 + threadIdx.x) * 8;
    f32x4 a = *(const f32x4*)(in + i);
    f32x4 c = *(const f32x4*)(in + i + 4);
    bf16x8 o;
    #pragma unroll
    for (int j = 0; j < 4; ++j) { o[j] = (__bf16)a[j]; o[j + 4] = (__bf16)c[j]; }
    *(bf16x8*)(out + i) = o;
}

// ---------------------------------------------------------------------------
// QKV GEMM: proven R3 128x128 m97-structure, BK=64, 4 waves,
// global_load_lds(16B) + XOR-granule swizzle. By-major tile order + XCD
// chunk (verified: halves HBM FETCH). Output: single [m][3072] bf16 buffer
// (natural GEMM layout, q-scale folded by col%192<64) - no scatter math.
// ---------------------------------------------------------------------------
__global__ __launch_bounds__(256)
void gemm_qkv(const __bf16* __restrict__ A, const __bf16* __restrict__ Bw,
              const float* __restrict__ bias, __bf16* __restrict__ qkv)
{
    constexpr int M = 16400;
    constexpr int K = 1024;
    constexpr int NT = 24 * 129;   // bx-tiles x by-tiles = 3096 = 8 x 387

    __shared__ __align__(16) __bf16 As[128 * 64];
    __shared__ __align__(16) __bf16 Bs[128 * 64];

    const int tid  = threadIdx.x;
    const int lane = tid & 63;
    const int wv   = tid >> 6;
    const int wr   = wv >> 1, wc = wv & 1;
    const int fr   = lane & 15, fq = lane >> 4;

    // XCD chunk (3096 = 8 x 387 exactly), by-major (bx fast -> A-panel reuse)
    const int xx = blockIdx.x & 7, jj = blockIdx.x >> 3;
    const int tile = xx * (NT / 8) + jj;
    const int by = tile / 24, bx = tile % 24;
    const int m0 = by * 128, n0 = bx * 128;

    const __bf16* aptr[4];
    const __bf16* bptr[4];
    int loff[4];
    #pragma unroll
    for (int qd = 0; qd < 4; ++qd) {
        const int s  = qd * 256 + tid;
        const int r  = s >> 3;
        const int c  = (s & 7) ^ (r & 7);
        loff[qd] = s * 8;
        int ar = m0 + r; if (ar > M - 1) ar = M - 1;
        aptr[qd] = A  + (size_t)ar * K + c * 8;
        bptr[qd] = Bw + (size_t)(n0 + r) * K + c * 8;
    }

    f32x4 acc[4][4];
    #pragma unroll
    for (int i = 0; i < 4; ++i)
        #pragma unroll
        for (int j = 0; j < 4; ++j)
            acc[i][j] = f32x4{0.f, 0.f, 0.f, 0.f};

    for (int kt = 0; kt < K / 64; ++kt) {
        const int kof = kt * 64;
        #pragma unroll
        for (int qd = 0; qd < 4; ++qd) {
            gload16(aptr[qd] + kof, &As[loff[qd]]);
            gload16(bptr[qd] + kof, &Bs[loff[qd]]);
        }
        __syncthreads();

        #pragma unroll
        for (int ks = 0; ks < 2; ++ks) {
            bf16x8 a[4], b[4];
            #pragma unroll
            for (int i = 0; i < 4; ++i) {
                const int ra = wr * 64 + i * 16 + fr;
                const int rb = wc * 64 + i * 16 + fr;
                const int cg = ((ks * 4 + fq) ^ (fr & 7)) * 8;
                a[i] = *(const bf16x8*)&As[ra * 64 + cg];
                b[i] = *(const bf16x8*)&Bs[rb * 64 + cg];
            }
            #pragma unroll
            for (int i = 0; i < 4; ++i)
                #pragma unroll
                for (int j = 0; j < 4; ++j)
                    acc[i][j] = mfma16(a[i], b[j], acc[i][j]);
        }
        __syncthreads();
    }

    // epilogue: natural [m][3072] store; fold 0.125*log2e into q cols
    #pragma unroll
    for (int ni = 0; ni < 4; ++ni) {
        const int col = n0 + wc * 64 + ni * 16 + fr;
        const float bv = bias[col];
        const float scale = ((col % 192) < 64) ? 0.18033688011112042f : 1.0f;
        #pragma unroll
        for (int mi = 0; mi < 4; ++mi) {
            #pragma unroll
            for (int j = 0; j < 4; ++j) {
                const int m = m0 + wr * 64 + mi * 16 + fq * 4 + j;
                if (m < M)
                    qkv[(size_t)m * 3072 + col] = (__bf16)((acc[mi][ni][j] + bv) * scale);
            }
        }
    }
}

// ---------------------------------------------------------------------------
// Dense-out GEMM: 128x128 m97-structure + XCD chunk (n-fast A-sharing)
// ---------------------------------------------------------------------------
__global__ __launch_bounds__(256)
void gemm_dense128(const __bf16* __restrict__ A, const __bf16* __restrict__ Bw,
                   const float* __restrict__ bias, float* __restrict__ f_out)
{
    constexpr int M = 16400;
    constexpr int K = 1024;

    __shared__ __align__(16) __bf16 As[128 * 64];
    __shared__ __align__(16) __bf16 Bs[128 * 64];

    const int tid  = threadIdx.x;
    const int lane = tid & 63;
    const int wv   = tid >> 6;
    const int wr   = wv >> 1, wc = wv & 1;
    const int fr   = lane & 15, fq = lane >> 4;

    const int xx = blockIdx.x & 7, jj = blockIdx.x >> 3;
    const int tile = xx * 129 + jj;
    const int m0 = (tile >> 3) * 128;
    const int n0 = (tile & 7) * 128;

    const __bf16* aptr[4];
    const __bf16* bptr[4];
    int loff[4];
    #pragma unroll
    for (int qd = 0; qd < 4; ++qd) {
        const int s  = qd * 256 + tid;
        const int r  = s >> 3;
        const int c  = (s & 7) ^ (r & 7);
        loff[qd] = s * 8;
        int ar = m0 + r; if (ar > M - 1) ar = M - 1;
        aptr[qd] = A  + (size_t)ar * K + c * 8;
        bptr[qd] = Bw + (size_t)(n0 + r) * K + c * 8;
    }

    f32x4 acc[4][4];
    #pragma unroll
    for (int i = 0; i < 4; ++i)
        #pragma unroll
        for (int j = 0; j < 4; ++j)
            acc[i][j] = f32x4{0.f, 0.f, 0.f, 0.f};

    for (int kt = 0; kt < K / 64; ++kt) {
        const int kof = kt * 64;
        #pragma unroll
        for (int qd = 0; qd < 4; ++qd) {
            gload16(aptr[qd] + kof, &As[loff[qd]]);
            gload16(bptr[qd] + kof, &Bs[loff[qd]]);
        }
        __syncthreads();

        #pragma unroll
        for (int ks = 0; ks < 2; ++ks) {
            bf16x8 a[4], b[4];
            #pragma unroll
            for (int i = 0; i < 4; ++i) {
                const int ra = wr * 64 + i * 16 + fr;
                const int rb = wc * 64 + i * 16 + fr;
                const int cg = ((ks * 4 + fq) ^ (fr & 7)) * 8;
                a[i] = *(const bf16x8*)&As[ra * 64 + cg];
                b[i] = *(const bf16x8*)&Bs[rb * 64 + cg];
            }
            #pragma unroll
            for (int i = 0; i < 4; ++i)
                #pragma unroll
                for (int j = 0; j < 4; ++j)
                    acc[i][j] = mfma16(a[i], b[j], acc[i][j]);
        }
        __syncthreads();
    }

    #pragma unroll
    for (int ni = 0; ni < 4; ++ni) {
        const int col = n0 + wc * 64 + ni * 16 + fr;
        const float bv = bias[col];
        #pragma unroll
        for (int mi = 0; mi < 4; ++mi) {
            #pragma unroll
            for (int j = 0; j < 4; ++j) {
                const int m = m0 + wr * 64 + mi * 16 + fq * 4 + j;
                if (m < M) f_out[(size_t)m * 1024 + col] = acc[mi][ni][j] + bv;
            }
        }
    }
}

// ---------------------------------------------------------------------------
// V transpose: reads V slice of qkv [m][3072] -> vt [bh][64][S2=1088]
// ---------------------------------------------------------------------------
__global__ __launch_bounds__(256)
void transpose_v(const __bf16* __restrict__ qkvb, __bf16* __restrict__ vt)
{
    constexpr int S = 1025, S2 = 1088;
    const int bh = blockIdx.y;
    const int bb = bh >> 4, hh = bh & 15;
    const int s0 = blockIdx.x * 64;
    const int sr = threadIdx.x >> 2, sq = threadIdx.x & 3;
    int srow = s0 + sr; if (srow > S - 1) srow = S - 1;
    const __bf16* src = qkvb + ((size_t)(bb * 1025) + srow) * 3072
                             + hh * 192 + 128 + sq * 16;
    bf16x8 v0 = *(const bf16x8*)src;
    bf16x8 v1 = *(const bf16x8*)(src + 8);
    __bf16* dst = vt + (size_t)bh * 64 * S2 + s0 + sr;
    #pragma unroll
    for (int i = 0; i < 8; ++i) {
        dst[(size_t)(sq * 16 + i) * S2]     = v0[i];
        dst[(size_t)(sq * 16 + 8 + i) * S2] = v1[i];
    }
}

// ---------------------------------------------------------------------------
// Flash attention, swapped QK^T. QBLK=128 (8 waves): halves K/V staging
// traffic per q-row. Q/K read directly from qkv [m][3072]; V from vt.
// Per-wave body identical to the verified R3/R6 version.
// ---------------------------------------------------------------------------
__global__ __launch_bounds__(512)
void attn_kernel(const __bf16* __restrict__ qkvb, const __bf16* __restrict__ vtb,
                 __bf16* __restrict__ ctxb)
{
    constexpr int S = 1025, S2 = 1088, ROW = 3072;
    const int tid  = threadIdx.x;
    const int lane = tid & 63;
    const int w    = tid >> 6;                 // 0..7
    const int fr   = lane & 15, fq = lane >> 4;

    // XCD chunk: 2304 = 8 x 288; qt fast -> same-head blocks co-resident
    const int xx = blockIdx.x & 7, jj = blockIdx.x >> 3;
    const int tile = xx * 288 + jj;
    const int bh = tile / 9;
    const int q0 = (tile % 9) * 128;
    const int bb = bh >> 4, hh = bh & 15;

    const __bf16* qp = qkvb + (size_t)(bb * 1025) * ROW + hh * 192;  // q at +0
    const __bf16* kp = qp + 64;                                      // k at +64
    const __bf16* vp = vtb + (size_t)bh * 64 * S2;

    __shared__ __align__(16) __bf16 Ks[64 * 64];
    __shared__ __align__(16) __bf16 Vs[64 * 64];
    __shared__ u32 Ps[8][16 * 33];

    // staging: 512 threads, 1 slot per tensor each
    const int r0 = tid >> 3, g0 = (tid & 7) ^ ((tid >> 3) & 7);

    int qrow = q0 + w * 16 + fr; if (qrow > S - 1) qrow = S - 1;
    const bf16x8 qa0 = *(const bf16x8*)(qp + (size_t)qrow * ROW + fq * 8);
    const bf16x8 qa1 = *(const bf16x8*)(qp + (size_t)qrow * ROW + 32 + fq * 8);

    f32x4 ctx[4];
    #pragma unroll
    for (int di = 0; di < 4; ++di) ctx[di] = f32x4{0.f, 0.f, 0.f, 0.f};
    float mrow = -1e30f;
    float lrow = 0.f;

    u32* psrow_w = &Ps[w][fr * 33];

    for (int kt = 0; kt < 17; ++kt) {
        const int kv0 = kt * 64;
        {
            int kr = kv0 + r0; if (kr > S - 1) kr = S - 1;
            gload16(kp + (size_t)kr * ROW + g0 * 8, &Ks[tid * 8]);
            gload16(vp + (size_t)r0 * S2 + kv0 + g0 * 8, &Vs[tid * 8]);
        }
        __syncthreads();

        f32x4 sc[4];
        #pragma unroll
        for (int ni = 0; ni < 4; ++ni) {
            const int row = ni * 16 + fr;
            bf16x8 kf0 = *(const bf16x8*)&Ks[row * 64 + ((fq    ) ^ (row & 7)) * 8];
            bf16x8 kf1 = *(const bf16x8*)&Ks[row * 64 + ((fq + 4) ^ (row & 7)) * 8];
            f32x4 z = f32x4{0.f, 0.f, 0.f, 0.f};
            z = mfma16(kf0, qa0, z);
            sc[ni] = mfma16(kf1, qa1, z);
        }
        if (kv0 + 64 > S) {
            #pragma unroll
            for (int ni = 0; ni < 4; ++ni)
                #pragma unroll
                for (int j = 0; j < 4; ++j)
                    if (kv0 + ni * 16 + fq * 4 + j >= S) sc[ni][j] = -1e30f;
        }

        float mt = sc[0][0];
        #pragma unroll
        for (int ni = 0; ni < 4; ++ni)
            #pragma unroll
            for (int j = 0; j < 4; ++j) mt = fmaxf(mt, sc[ni][j]);
        mt = fmaxf(mt, __shfl_xor(mt, 16, 64));
        mt = fmaxf(mt, __shfl_xor(mt, 32, 64));

        if (__any(mt > mrow + 8.0f)) {
            const float mnew = fmaxf(mrow, mt);
            const float alpha = exp2fast(mrow - mnew);
            mrow = mnew;
            lrow *= alpha;
            float av[4];
            #pragma unroll
            for (int j = 0; j < 4; ++j) av[j] = __shfl(alpha, fq * 4 + j, 64);
            #pragma unroll
            for (int di = 0; di < 4; ++di) {
                ctx[di][0] *= av[0]; ctx[di][1] *= av[1];
                ctx[di][2] *= av[2]; ctx[di][3] *= av[3];
            }
        }

        float p[4][4];
        float s = 0.f;
        #pragma unroll
        for (int ni = 0; ni < 4; ++ni)
            #pragma unroll
            for (int j = 0; j < 4; ++j) {
                p[ni][j] = exp2fast(sc[ni][j] - mrow);
                s += p[ni][j];
            }
        s += __shfl_xor(s, 16, 64);
        s += __shfl_xor(s, 32, 64);
        lrow += s;

        #pragma unroll
        for (int ni = 0; ni < 4; ++ni) {
            #pragma unroll
            for (int h = 0; h < 2; ++h) {
                unsigned short lo = __builtin_bit_cast(unsigned short, (__bf16)p[ni][2 * h]);
                unsigned short hi = __builtin_bit_cast(unsigned short, (__bf16)p[ni][2 * h + 1]);
                psrow_w[fq * 8 + ni * 2 + h] = (u32)lo | ((u32)hi << 16);
            }
        }
        u32x4 pav[2];
        #pragma unroll
        for (int ks = 0; ks < 2; ++ks)
            #pragma unroll
            for (int t = 0; t < 4; ++t) {
                const int slot = (2 * (fq & 1) + (t >> 1)) * 8
                               + (2 * ks + (fq >> 1)) * 2 + (t & 1);
                pav[ks][t] = psrow_w[slot];
            }

        #pragma unroll
        for (int ks = 0; ks < 2; ++ks) {
            const bf16x8 pa = __builtin_bit_cast(bf16x8, pav[ks]);
            #pragma unroll
            for (int di = 0; di < 4; ++di) {
                const int row = di * 16 + fr;
                bf16x8 vf = *(const bf16x8*)&Vs[row * 64 + ((ks * 4 + fq) ^ (row & 7)) * 8];
                ctx[di] = mfma16(pa, vf, ctx[di]);
            }
        }
        __syncthreads();
    }

    float linv[4];
    #pragma unroll
    for (int j = 0; j < 4; ++j) linv[j] = 1.0f / __shfl(lrow, fq * 4 + j, 64);
    #pragma unroll
    for (int di = 0; di < 4; ++di) {
        #pragma unroll
        for (int j = 0; j < 4; ++j) {
            const int qg = q0 + w * 16 + fq * 4 + j;
            if (qg < S) {
                ctxb[((size_t)bb * 1025 + qg) * 1024 + hh * 64 + di * 16 + fr] =
                    (__bf16)(ctx[di][j] * linv[j]);
            }
        }
    }
}

// ---------------------------------------------------------------------------
extern "C" void kernel_launch(void* const* d_in, const int* in_sizes, int n_in,
                              void* d_out, int out_size, void* d_ws, size_t ws_size,
                              hipStream_t stream)
{
    const float* hs      = (const float*)d_in[0];
    const float* w_qkv   = (const float*)d_in[1];
    const float* b_qkv   = (const float*)d_in[2];
    const float* w_dense = (const float*)d_in[3];
    const float* b_dense = (const float*)d_in[4];

    const size_t nHS  = (size_t)16 * 1025 * 1024;    // 16,793,600
    const size_t nWQ  = (size_t)3072 * 1024;         //  3,145,728
    const size_t nWD  = (size_t)1024 * 1024;         //  1,048,576
    const size_t nQKV = (size_t)16400 * 3072;        // 50,380,800

    __bf16* hsb     = (__bf16*)d_ws;
    __bf16* wqkvb   = hsb + nHS;
    __bf16* wdenseb = wqkvb + nWQ;
    __bf16* qkvb    = wdenseb + nWD;
    __bf16* ctxb    = qkvb + nQKV;
    __bf16* vtb     = ctxb + nHS;

    convert3_kernel<<<dim3(8200 + 1536 + 512), dim3(256), 0, stream>>>(
        hs, hsb, 8200, w_qkv, wqkvb, 1536, w_dense, wdenseb);

    gemm_qkv<<<dim3(24 * 129), dim3(256), 0, stream>>>(
        hsb, wqkvb, b_qkv, qkvb);

    transpose_v<<<dim3(17, 256), dim3(256), 0, stream>>>(qkvb, vtb);

    attn_kernel<<<dim3(8 * 288), dim3(512), 0, stream>>>(qkvb, vtb, ctxb);

    gemm_dense128<<<dim3(8 * 129), dim3(256), 0, stream>>>(
        ctxb, wdenseb, b_dense, (float*)d_out);
}

// Round 8
// 389.654 us; speedup vs baseline: 1.2497x; 1.1233x over previous
//
#include <hip/hip_runtime.h>
#include <math.h>

typedef float f32x4 __attribute__((ext_vector_type(4)));
typedef __bf16 bf16x8 __attribute__((ext_vector_type(8)));
typedef unsigned int u32;
typedef u32 u32x4 __attribute__((ext_vector_type(4)));

#define AS1 __attribute__((address_space(1)))
#define AS3 __attribute__((address_space(3)))

static __device__ __forceinline__ void gload16(const void* g, void* l) {
    __builtin_amdgcn_global_load_lds((const AS1 u32*)g, (AS3 u32*)l, 16, 0, 0);
}
static __device__ __forceinline__ f32x4 mfma16(bf16x8 a, bf16x8 b, f32x4 c) {
    return __builtin_amdgcn_mfma_f32_16x16x32_bf16(a, b, c, 0, 0, 0);
}
static __device__ __forceinline__ float exp2fast(float x) {
    return __builtin_amdgcn_exp2f(x);
}

// ---------------------------------------------------------------------------
// fused fp32 -> bf16 convert over 3 segments (each a multiple of 2048 elems)
// ---------------------------------------------------------------------------
__global__ __launch_bounds__(256)
void convert3_kernel(const float* __restrict__ in0, __bf16* __restrict__ out0, int nb0,
                     const float* __restrict__ in1, __bf16* __restrict__ out1, int nb1,
                     const float* __restrict__ in2, __bf16* __restrict__ out2)
{
    int b = blockIdx.x;
    const float* in; __bf16* out;
    if (b < nb0)            { in = in0; out = out0; }
    else if (b < nb0 + nb1) { in = in1; out = out1; b -= nb0; }
    else                    { in = in2; out = out2; b -= nb0 + nb1; }
    const size_t i = ((size_t)b * 256 + threadIdx.x) * 8;
    f32x4 a = *(const f32x4*)(in + i);
    f32x4 c = *(const f32x4*)(in + i + 4);
    bf16x8 o;
    #pragma unroll
    for (int j = 0; j < 4; ++j) { o[j] = (__bf16)a[j]; o[j + 4] = (__bf16)c[j]; }
    *(bf16x8*)(out + i) = o;
}

// ---------------------------------------------------------------------------
// GEMM 256M x 128N tile, BK=64, 8 waves (4M x 2N, wave tile 64x64 = R7's
// proven per-wave code), single-buffer LDS 48KB, 2-barrier m97 structure,
// gload_lds(16B) + XOR-granule swizzle, by-major XCD chunking.
// Higher staging intensity than 128x128: 310cy compute / 48KB vs 155/32KB.
// MODE 0: C -> qkv [m][3072] bf16, q-cols scaled. MODE 1: C -> f32 out.
// ---------------------------------------------------------------------------
template<int MODE>
__global__ __launch_bounds__(512)
void gemm_big(const __bf16* __restrict__ A, const __bf16* __restrict__ Bw,
              const float* __restrict__ bias, __bf16* __restrict__ qkv,
              float* __restrict__ f_out)
{
    constexpr int M = 16400;
    constexpr int K = 1024;
    constexpr int NBX = (MODE == 0) ? 24 : 8;       // N / 128
    constexpr int NOUT = (MODE == 0) ? 3072 : 1024;
    constexpr int CHUNK = (65 * NBX) / 8;           // tiles per XCD (exact)

    __shared__ __align__(16) __bf16 As[256 * 64];   // 32 KB
    __shared__ __align__(16) __bf16 Bs[128 * 64];   // 16 KB

    const int tid  = threadIdx.x;
    const int lane = tid & 63;
    const int wv   = tid >> 6;          // 0..7
    const int wrm  = wv >> 1;           // 0..3  M quarter (64 rows)
    const int wcn  = wv & 1;            // 0..1  N half (64 cols)
    const int fr   = lane & 15, fq = lane >> 4;

    // XCD chunk (exact multiple of 8), by-major (bx fast -> A-panel reuse)
    const int xx = blockIdx.x & 7, jj = blockIdx.x >> 3;
    const int tile = xx * CHUNK + jj;
    const int by = tile / NBX, bx = tile % NBX;
    const int m0 = by * 256, n0 = bx * 128;

    // ---- staging precompute (linear LDS dest, inverse-swizzled gsrc) ----
    const __bf16* aptr[4]; int aoff[4];
    #pragma unroll
    for (int qd = 0; qd < 4; ++qd) {
        const int s = qd * 512 + tid;            // 0..2047
        const int r = s >> 3;                    // 0..255
        const int c = (s & 7) ^ (r & 7);
        aoff[qd] = s * 8;
        int ar = m0 + r; if (ar > M - 1) ar = M - 1;
        aptr[qd] = A + (size_t)ar * K + c * 8;
    }
    const __bf16* bptr[2]; int boff[2];
    #pragma unroll
    for (int l = 0; l < 2; ++l) {
        const int s = l * 512 + tid;             // 0..1023
        const int r = s >> 3;                    // 0..127
        const int c = (s & 7) ^ (r & 7);
        boff[l] = s * 8;
        bptr[l] = Bw + (size_t)(n0 + r) * K + c * 8;
    }

    f32x4 acc[4][4];
    #pragma unroll
    for (int i = 0; i < 4; ++i)
        #pragma unroll
        for (int j = 0; j < 4; ++j)
            acc[i][j] = f32x4{0.f, 0.f, 0.f, 0.f};

    for (int kt = 0; kt < K / 64; ++kt) {
        const int kof = kt * 64;
        #pragma unroll
        for (int qd = 0; qd < 4; ++qd) gload16(aptr[qd] + kof, &As[aoff[qd]]);
        #pragma unroll
        for (int l = 0; l < 2; ++l)   gload16(bptr[l] + kof, &Bs[boff[l]]);
        __syncthreads();

        #pragma unroll
        for (int ks = 0; ks < 2; ++ks) {
            bf16x8 a[4], b[4];
            #pragma unroll
            for (int i = 0; i < 4; ++i) {
                const int ra = wrm * 64 + i * 16 + fr;
                const int rb = wcn * 64 + i * 16 + fr;
                const int cga = ((ks * 4 + fq) ^ (ra & 7)) * 8;
                const int cgb = ((ks * 4 + fq) ^ (rb & 7)) * 8;
                a[i] = *(const bf16x8*)&As[ra * 64 + cga];
                b[i] = *(const bf16x8*)&Bs[rb * 64 + cgb];
            }
            #pragma unroll
            for (int i = 0; i < 4; ++i)
                #pragma unroll
                for (int j = 0; j < 4; ++j)
                    acc[i][j] = mfma16(a[i], b[j], acc[i][j]);
        }
        __syncthreads();
    }

    // ---- epilogue ----
    #pragma unroll
    for (int ni = 0; ni < 4; ++ni) {
        const int col = n0 + wcn * 64 + ni * 16 + fr;
        const float bv = bias[col];
        if constexpr (MODE == 0) {
            const float scale = ((col % 192) < 64) ? 0.18033688011112042f : 1.0f;
            #pragma unroll
            for (int mi = 0; mi < 4; ++mi) {
                #pragma unroll
                for (int j = 0; j < 4; ++j) {
                    const int m = m0 + wrm * 64 + mi * 16 + fq * 4 + j;
                    if (m < M)
                        qkv[(size_t)m * NOUT + col] =
                            (__bf16)((acc[mi][ni][j] + bv) * scale);
                }
            }
        } else {
            #pragma unroll
            for (int mi = 0; mi < 4; ++mi) {
                #pragma unroll
                for (int j = 0; j < 4; ++j) {
                    const int m = m0 + wrm * 64 + mi * 16 + fq * 4 + j;
                    if (m < M) f_out[(size_t)m * NOUT + col] = acc[mi][ni][j] + bv;
                }
            }
        }
    }
}

// ---------------------------------------------------------------------------
// V transpose: reads V slice of qkv [m][3072] -> vt [bh][64][S2=1088]
// ---------------------------------------------------------------------------
__global__ __launch_bounds__(256)
void transpose_v(const __bf16* __restrict__ qkvb, __bf16* __restrict__ vt)
{
    constexpr int S = 1025, S2 = 1088;
    const int bh = blockIdx.y;
    const int bb = bh >> 4, hh = bh & 15;
    const int s0 = blockIdx.x * 64;
    const int sr = threadIdx.x >> 2, sq = threadIdx.x & 3;
    int srow = s0 + sr; if (srow > S - 1) srow = S - 1;
    const __bf16* src = qkvb + ((size_t)(bb * 1025) + srow) * 3072
                             + hh * 192 + 128 + sq * 16;
    bf16x8 v0 = *(const bf16x8*)src;
    bf16x8 v1 = *(const bf16x8*)(src + 8);
    __bf16* dst = vt + (size_t)bh * 64 * S2 + s0 + sr;
    #pragma unroll
    for (int i = 0; i < 8; ++i) {
        dst[(size_t)(sq * 16 + i) * S2]     = v0[i];
        dst[(size_t)(sq * 16 + 8 + i) * S2] = v1[i];
    }
}

// ---------------------------------------------------------------------------
// Flash attention, swapped QK^T, QBLK=128 (8 waves). Unchanged from R7.
// ---------------------------------------------------------------------------
__global__ __launch_bounds__(512)
void attn_kernel(const __bf16* __restrict__ qkvb, const __bf16* __restrict__ vtb,
                 __bf16* __restrict__ ctxb)
{
    constexpr int S = 1025, S2 = 1088, ROW = 3072;
    const int tid  = threadIdx.x;
    const int lane = tid & 63;
    const int w    = tid >> 6;
    const int fr   = lane & 15, fq = lane >> 4;

    const int xx = blockIdx.x & 7, jj = blockIdx.x >> 3;
    const int tile = xx * 288 + jj;
    const int bh = tile / 9;
    const int q0 = (tile % 9) * 128;
    const int bb = bh >> 4, hh = bh & 15;

    const __bf16* qp = qkvb + (size_t)(bb * 1025) * ROW + hh * 192;
    const __bf16* kp = qp + 64;
    const __bf16* vp = vtb + (size_t)bh * 64 * S2;

    __shared__ __align__(16) __bf16 Ks[64 * 64];
    __shared__ __align__(16) __bf16 Vs[64 * 64];
    __shared__ u32 Ps[8][16 * 33];

    const int r0 = tid >> 3, g0 = (tid & 7) ^ ((tid >> 3) & 7);

    int qrow = q0 + w * 16 + fr; if (qrow > S - 1) qrow = S - 1;
    const bf16x8 qa0 = *(const bf16x8*)(qp + (size_t)qrow * ROW + fq * 8);
    const bf16x8 qa1 = *(const bf16x8*)(qp + (size_t)qrow * ROW + 32 + fq * 8);

    f32x4 ctx[4];
    #pragma unroll
    for (int di = 0; di < 4; ++di) ctx[di] = f32x4{0.f, 0.f, 0.f, 0.f};
    float mrow = -1e30f;
    float lrow = 0.f;

    u32* psrow_w = &Ps[w][fr * 33];

    for (int kt = 0; kt < 17; ++kt) {
        const int kv0 = kt * 64;
        {
            int kr = kv0 + r0; if (kr > S - 1) kr = S - 1;
            gload16(kp + (size_t)kr * ROW + g0 * 8, &Ks[tid * 8]);
            gload16(vp + (size_t)r0 * S2 + kv0 + g0 * 8, &Vs[tid * 8]);
        }
        __syncthreads();

        f32x4 sc[4];
        #pragma unroll
        for (int ni = 0; ni < 4; ++ni) {
            const int row = ni * 16 + fr;
            bf16x8 kf0 = *(const bf16x8*)&Ks[row * 64 + ((fq    ) ^ (row & 7)) * 8];
            bf16x8 kf1 = *(const bf16x8*)&Ks[row * 64 + ((fq + 4) ^ (row & 7)) * 8];
            f32x4 z = f32x4{0.f, 0.f, 0.f, 0.f};
            z = mfma16(kf0, qa0, z);
            sc[ni] = mfma16(kf1, qa1, z);
        }
        if (kv0 + 64 > S) {
            #pragma unroll
            for (int ni = 0; ni < 4; ++ni)
                #pragma unroll
                for (int j = 0; j < 4; ++j)
                    if (kv0 + ni * 16 + fq * 4 + j >= S) sc[ni][j] = -1e30f;
        }

        float mt = sc[0][0];
        #pragma unroll
        for (int ni = 0; ni < 4; ++ni)
            #pragma unroll
            for (int j = 0; j < 4; ++j) mt = fmaxf(mt, sc[ni][j]);
        mt = fmaxf(mt, __shfl_xor(mt, 16, 64));
        mt = fmaxf(mt, __shfl_xor(mt, 32, 64));

        if (__any(mt > mrow + 8.0f)) {
            const float mnew = fmaxf(mrow, mt);
            const float alpha = exp2fast(mrow - mnew);
            mrow = mnew;
            lrow *= alpha;
            float av[4];
            #pragma unroll
            for (int j = 0; j < 4; ++j) av[j] = __shfl(alpha, fq * 4 + j, 64);
            #pragma unroll
            for (int di = 0; di < 4; ++di) {
                ctx[di][0] *= av[0]; ctx[di][1] *= av[1];
                ctx[di][2] *= av[2]; ctx[di][3] *= av[3];
            }
        }

        float p[4][4];
        float s = 0.f;
        #pragma unroll
        for (int ni = 0; ni < 4; ++ni)
            #pragma unroll
            for (int j = 0; j < 4; ++j) {
                p[ni][j] = exp2fast(sc[ni][j] - mrow);
                s += p[ni][j];
            }
        s += __shfl_xor(s, 16, 64);
        s += __shfl_xor(s, 32, 64);
        lrow += s;

        #pragma unroll
        for (int ni = 0; ni < 4; ++ni) {
            #pragma unroll
            for (int h = 0; h < 2; ++h) {
                unsigned short lo = __builtin_bit_cast(unsigned short, (__bf16)p[ni][2 * h]);
                unsigned short hi = __builtin_bit_cast(unsigned short, (__bf16)p[ni][2 * h + 1]);
                psrow_w[fq * 8 + ni * 2 + h] = (u32)lo | ((u32)hi << 16);
            }
        }
        u32x4 pav[2];
        #pragma unroll
        for (int ks = 0; ks < 2; ++ks)
            #pragma unroll
            for (int t = 0; t < 4; ++t) {
                const int slot = (2 * (fq & 1) + (t >> 1)) * 8
                               + (2 * ks + (fq >> 1)) * 2 + (t & 1);
                pav[ks][t] = psrow_w[slot];
            }

        #pragma unroll
        for (int ks = 0; ks < 2; ++ks) {
            const bf16x8 pa = __builtin_bit_cast(bf16x8, pav[ks]);
            #pragma unroll
            for (int di = 0; di < 4; ++di) {
                const int row = di * 16 + fr;
                bf16x8 vf = *(const bf16x8*)&Vs[row * 64 + ((ks * 4 + fq) ^ (row & 7)) * 8];
                ctx[di] = mfma16(pa, vf, ctx[di]);
            }
        }
        __syncthreads();
    }

    float linv[4];
    #pragma unroll
    for (int j = 0; j < 4; ++j) linv[j] = 1.0f / __shfl(lrow, fq * 4 + j, 64);
    #pragma unroll
    for (int di = 0; di < 4; ++di) {
        #pragma unroll
        for (int j = 0; j < 4; ++j) {
            const int qg = q0 + w * 16 + fq * 4 + j;
            if (qg < S) {
                ctxb[((size_t)bb * 1025 + qg) * 1024 + hh * 64 + di * 16 + fr] =
                    (__bf16)(ctx[di][j] * linv[j]);
            }
        }
    }
}

// ---------------------------------------------------------------------------
extern "C" void kernel_launch(void* const* d_in, const int* in_sizes, int n_in,
                              void* d_out, int out_size, void* d_ws, size_t ws_size,
                              hipStream_t stream)
{
    const float* hs      = (const float*)d_in[0];
    const float* w_qkv   = (const float*)d_in[1];
    const float* b_qkv   = (const float*)d_in[2];
    const float* w_dense = (const float*)d_in[3];
    const float* b_dense = (const float*)d_in[4];

    const size_t nHS  = (size_t)16 * 1025 * 1024;
    const size_t nWQ  = (size_t)3072 * 1024;
    const size_t nWD  = (size_t)1024 * 1024;
    const size_t nQKV = (size_t)16400 * 3072;

    __bf16* hsb     = (__bf16*)d_ws;
    __bf16* wqkvb   = hsb + nHS;
    __bf16* wdenseb = wqkvb + nWQ;
    __bf16* qkvb    = wdenseb + nWD;
    __bf16* ctxb    = qkvb + nQKV;
    __bf16* vtb     = ctxb + nHS;

    convert3_kernel<<<dim3(8200 + 1536 + 512), dim3(256), 0, stream>>>(
        hs, hsb, 8200, w_qkv, wqkvb, 1536, w_dense, wdenseb);

    // QKV: 65 x 24 tiles of 256x128 = 1560 = 8 x 195
    gemm_big<0><<<dim3(65 * 24), dim3(512), 0, stream>>>(
        hsb, wqkvb, b_qkv, qkvb, nullptr);

    transpose_v<<<dim3(17, 256), dim3(256), 0, stream>>>(qkvb, vtb);

    attn_kernel<<<dim3(8 * 288), dim3(512), 0, stream>>>(qkvb, vtb, ctxb);

    // dense: 65 x 8 tiles of 256x128 = 520 = 8 x 65
    gemm_big<1><<<dim3(65 * 8), dim3(512), 0, stream>>>(
        ctxb, wdenseb, b_dense, nullptr, (float*)d_out);
}